// Round 9
// baseline (286.967 us; speedup 1.0000x reference)
//
#include <hip/hip_runtime.h>
#include <hip/hip_bf16.h>

typedef __hip_bfloat16 bf16;
typedef __attribute__((ext_vector_type(8))) short s16x8;
typedef __attribute__((ext_vector_type(4))) float f32x4;

constexpr int cN = 128, cC = 64, cT = 64, cV = 25, cK = 3, cMID = 64, cKM = 192, cTV = 1600;
constexpr int cPC = 2048;                 // padded col space: col' = t*32 + v
constexpr float cEPS = 1e-5f;

// All intermediates in BSS: zero d_ws dependency.
__device__ float g_tmp[cN * cC * cV];
__device__ float g_x1 [cN * cKM * cV];
__device__ float g_x2 [cN * cKM * cV];
__device__ float g_ada[cN * cK * cV * cV];
// pre_x padded-flat [n][o][2048] (v>=25 written as exact 0)
__device__ ushort g_pre32[(size_t)cN * cKM * cPC];          // 100.7 MB
// Unified Z in B-fragment order, padded cols: [n][oct 0..31][2048][8].
// Octets 0..23 = y channels (gm_y2), 24..31 = x channels (k_xt).
__device__ ushort g_ztP[(size_t)cN * 32 * cPC * 8];         // 134.2 MB
// Folded weights in A-FRAGMENT order: [k-step][m-frag(12)][lane(64)][8]
__device__ ushort g_WpreF[2 * 12 * 512];
__device__ ushort g_WcatF[8 * 12 * 512];
__device__ float g_bpre [cKM];
__device__ float g_cterm[cKM];

__device__ __forceinline__ float b2f(bf16 v){ return __bfloat162float(v); }
__device__ __forceinline__ bf16  f2b(float v){ return __float2bfloat16(v); }
__device__ __forceinline__ ushort f2bu(float v){ return __builtin_bit_cast(ushort, __float2bfloat16(v)); }

// ---------------------------------------------------------------------------
// 0) fold bn into weights/biases, write bf16 weights in A-frag order.
// ---------------------------------------------------------------------------
__global__ void k_fold(const float* __restrict__ Wpre, const float* __restrict__ bpre,
                       const float* __restrict__ bnpre,
                       const float* __restrict__ Wpost, const float* __restrict__ bpost,
                       const float* __restrict__ bnpost,
                       const float* __restrict__ Wdown, const float* __restrict__ bdown,
                       const float* __restrict__ bndown){
  __shared__ float sPre[cKM], sPost[cKM], sDown[cKM];
  int tid = threadIdx.x;
  if (tid < cKM){
    float sp = bnpre[tid] * rsqrtf(bnpre[3*cKM+tid] + cEPS);
    sPre[tid] = sp;
    g_bpre[tid] = bpre[tid]*sp + bnpre[cKM+tid] - bnpre[2*cKM+tid]*sp;
    float sP = bnpost[tid] * rsqrtf(bnpost[3*cKM+tid] + cEPS);
    float sD = bndown[tid] * rsqrtf(bndown[3*cKM+tid] + cEPS);
    sPost[tid] = sP; sDown[tid] = sD;
    g_cterm[tid] = bpost[tid]*sP + bnpost[cKM+tid] - bnpost[2*cKM+tid]*sP
                 + bdown[tid]*sD + bndown[cKM+tid] - bndown[2*cKM+tid]*sD;
  }
  __syncthreads();
  // frag index: dst = (step*12 + o/16)*512 + ((g<<4)|l15)*8 + j
  for (int idx = tid; idx < cKM*cC; idx += 256){
    int o = idx >> 6, k = idx & 63;
    int step = k >> 5, g = (k >> 3) & 3, j = k & 7;
    int dst = ((step*12 + (o>>4)) << 9) + (((g<<4) | (o&15)) << 3) + j;
    g_WpreF[dst] = f2bu(Wpre[idx] * sPre[o]);
  }
  for (int idx = tid; idx < cKM*256; idx += 256){
    int o = idx >> 8, k = idx & 255;
    float w = (k < cKM) ? Wpost[o*cKM + k] * sPost[o]
                        : Wdown[o*cC + (k - cKM)] * sDown[o];
    int step = k >> 5, g = (k >> 3) & 3, j = k & 7;
    int dst = ((step*12 + (o>>4)) << 9) + (((g<<4) | (o&15)) << 3) + j;
    g_WcatF[dst] = f2bu(w);
  }
}

// ---------------------------------------------------------------------------
// 1) g_tmp[n,c,v] = mean_t x[n,c,t,v]
// ---------------------------------------------------------------------------
__global__ void gm_tmp(const float* __restrict__ x){
  int b = blockIdx.x;
  int l = threadIdx.x;
  if (l >= cV) return;
  const float* p = x + (size_t)b * cTV + l;
  float s = 0.f;
  #pragma unroll
  for (int t = 0; t < cT; ++t) s += p[t * cV];
  g_tmp[b * cV + l] = s * (1.f / cT);
}

// ---------------------------------------------------------------------------
// 2) x1/x2 1x1 conv on mean
// ---------------------------------------------------------------------------
__global__ void gm_x1x2(const float* __restrict__ W1, const float* __restrict__ b1,
                        const float* __restrict__ W2, const float* __restrict__ b2){
  __shared__ float tl[cC * cV];
  __shared__ float w1[48 * cC];
  __shared__ float w2[48 * cC];
  int n = blockIdx.x >> 2, og = blockIdx.x & 3;
  int tid = threadIdx.x;
  int obase = og * 48;
  for (int i = tid; i < cC * cV; i += 256) tl[i] = g_tmp[n * cC * cV + i];
  for (int i = tid; i < 48 * cC; i += 256){
    w1[i] = W1[obase * cC + i];
    w2[i] = W2[obase * cC + i];
  }
  __syncthreads();
  for (int idx = tid; idx < 48 * cV; idx += 256){
    int j = idx / cV, v = idx % cV;
    int o = obase + j;
    float s1 = b1[o], s2 = b2[o];
    #pragma unroll
    for (int c = 0; c < cC; ++c){
      float t = tl[c * cV + v];
      s1 += w1[j * cC + c] * t;
      s2 += w2[j * cC + c] * t;
    }
    g_x1[((size_t)n * cKM + o) * cV + v] = s1;
    g_x2[((size_t)n * cKM + o) * cV + v] = s2;
  }
}

// ---------------------------------------------------------------------------
// 3) ada softmax
// ---------------------------------------------------------------------------
__global__ void gm_ada(const float* __restrict__ beta){
  __shared__ float a1[cMID * cV];
  __shared__ float a2[cMID * cV];
  __shared__ float al[cV * cV];
  int b = blockIdx.x; int n = b / cK, k = b % cK;
  int tid = threadIdx.x;
  const float* p1 = g_x1 + ((size_t)n * cKM + k * cMID) * cV;
  const float* p2 = g_x2 + ((size_t)n * cKM + k * cMID) * cV;
  for (int i = tid; i < cMID * cV; i += 128){ a1[i] = p1[i]; a2[i] = p2[i]; }
  __syncthreads();
  for (int idx = tid; idx < cV * cV; idx += 128){
    int v = idx / cV, w = idx % cV;
    float s = 0.f;
    #pragma unroll
    for (int c = 0; c < cMID; ++c) s += a1[c * cV + v] * a2[c * cV + w];
    al[idx] = s;
  }
  __syncthreads();
  float b0 = beta[0];
  if (tid < cV){
    int w = tid;
    float m = -1e30f;
    for (int v = 0; v < cV; ++v) m = fmaxf(m, al[v * cV + w]);
    float s = 0.f;
    for (int v = 0; v < cV; ++v) s += expf(al[v * cV + w] - m);
    float inv = b0 / s;
    for (int v = 0; v < cV; ++v)
      g_ada[(size_t)b * cV * cV + v * cV + w] = expf(al[v * cV + w] - m) * inv;
  }
}

// ---------------------------------------------------------------------------
// 3b) k_xt: x (f32) -> g_ztP octets 24..31 (bf16 frag order, padded cols).
//     grid = N*8 (256 padded cols each), 256 thr.
// ---------------------------------------------------------------------------
__global__ __launch_bounds__(256) void k_xt(const float* __restrict__ x){
  int n = blockIdx.x >> 3, tile = blockIdx.x & 7;
  int col = tile * 256 + threadIdx.x;       // padded col
  int t = col >> 5, v = col & 31;
  const float* xp = x + (size_t)n * cC * cTV + t * cV + v;
  ushort* zp = g_ztP + (((size_t)n * 32 + 24) * cPC + col) * 8;
  bool ok = (v < cV);
  #pragma unroll
  for (int oct = 0; oct < 8; ++oct){
    ushort u[8];
    #pragma unroll
    for (int j = 0; j < 8; ++j)
      u[j] = ok ? f2bu(xp[(size_t)(oct * 8 + j) * cTV]) : (ushort)0;
    *(uint4*)(zp + (size_t)oct * cPC * 8) = *(const uint4*)u;
  }
}

// ---------------------------------------------------------------------------
// 4+6) MFMA GEMM, LDS-staged Z (linear, conflict-free), frag-ordered A from L2.
//   C[192 x 64 padded cols] per (n, coltile of 2048).  4 waves.
//   MODE 0: K=64  (x octets 24..31) -> g_pre32 (bf16, relu, pads=0)
//   MODE 1: K=256 (octets 0..31)    -> d_out (f32, relu, pads skipped)
// ---------------------------------------------------------------------------
template<int MODE>
__global__ __launch_bounds__(256) void gm_mm(float* __restrict__ outf){
  constexpr int KTOT = MODE ? 256 : 64;
  constexpr int NOCT = KTOT / 8;                  // 32 or 8
  __shared__ ushort Zl[NOCT * 512];               // [oct][col 64][8]
  int bid = (int)(blockIdx.x & 7) * 512 + ((int)blockIdx.x >> 3);  // XCD swizzle
  int n = bid >> 5, ctile = bid & 31;
  int colb = ctile * 64;
  int tid = threadIdx.x;
  int lane = tid & 63, wv = tid >> 6, g = lane >> 4, l15 = lane & 15;

  const ushort* WF  = MODE ? g_WcatF : g_WpreF;
  const float*  cbp = MODE ? g_cterm : g_bpre;
  const ushort* zbase = g_ztP + ((size_t)n * 32 + (MODE ? 0 : 24)) * cPC * 8;

  // ---- stage Z tile: NOCT octets x 64 cols x 16B, fully linear ----
  #pragma unroll
  for (int i0 = 0; i0 < NOCT * 64; i0 += 256){
    int i = i0 + tid;
    int oct = i >> 6, l = i & 63;
    *(uint4*)&Zl[(size_t)i * 8] =
        *(const uint4*)(zbase + ((size_t)oct * cPC + colb + l) * 8);
  }
  __syncthreads();

  f32x4 acc[3][4];
  #pragma unroll
  for (int a = 0; a < 3; ++a)
    #pragma unroll
    for (int b = 0; b < 4; ++b) acc[a][b] = (f32x4){0.f,0.f,0.f,0.f};

  #pragma unroll
  for (int kb = 0; kb < KTOT; kb += 32){
    s16x8 av[3], bv[4];
    #pragma unroll
    for (int mf = 0; mf < 3; ++mf)
      av[mf] = *(const s16x8*)(WF + (((kb>>5)*12 + 3*wv + mf) << 9) + lane*8);
    int oct0 = kb >> 3;
    #pragma unroll
    for (int nf = 0; nf < 4; ++nf)
      bv[nf] = *(const s16x8*)&Zl[((oct0 + g) << 9) + ((16*nf + l15) << 3)];
    #pragma unroll
    for (int mf = 0; mf < 3; ++mf)
      #pragma unroll
      for (int nf = 0; nf < 4; ++nf)
        acc[mf][nf] = __builtin_amdgcn_mfma_f32_16x16x32_bf16(av[mf], bv[nf], acc[mf][nf], 0, 0, 0);
  }

  #pragma unroll
  for (int mf = 0; mf < 3; ++mf){
    #pragma unroll
    for (int q = 0; q < 4; ++q){
      int o = 48*wv + 16*mf + 4*g + q;
      float ct = cbp[o];
      #pragma unroll
      for (int nf = 0; nf < 4; ++nf){
        int col = colb + 16*nf + l15;          // padded col
        int t = col >> 5, v = col & 31;
        float val = fmaxf(acc[mf][nf][q] + ct, 0.f);
        if (MODE){
          if (v < cV) outf[((size_t)n*cKM + o)*cTV + t*cV + v] = val;
        } else {
          g_pre32[((size_t)n*cKM + o)*cPC + col] = (v < cV) ? f2bu(val) : (ushort)0;
        }
      }
    }
  }
}

// ---------------------------------------------------------------------------
// 5) y = pre_x @ Adyn via MFMA -> g_ztP octets 0..23 (padded cols).
//    8 waves/block = one k-octet; wave handles one (n,r).
// ---------------------------------------------------------------------------
__global__ __launch_bounds__(512) void gm_y2(const float* __restrict__ A,
                                             const float* __restrict__ alpha){
  __shared__ ushort yst[8][cT * cV];     // 8 x 3200 B
  int tid = threadIdx.x;
  int wv = tid >> 6, lane = tid & 63, g = lane >> 4, l15 = lane & 15;
  int bid = blockIdx.x;
  int n = bid / 24, oct = bid % 24;
  int r = oct * 8 + wv;
  int k = r / cMID;
  float a0 = alpha[0];

  const float* x1p = g_x1 + ((size_t)n * cKM + r) * cV;
  const float* x2p = g_x2 + ((size_t)n * cKM + r) * cV;
  const float* Ak   = A + k * cV * cV;
  const float* adak = g_ada + ((size_t)n * cK + k) * cV * cV;

  float w0 = x2p[l15];
  int w1i = 16 + l15;
  float w1 = (w1i < cV) ? x2p[w1i] : 0.f;

  s16x8 bv0, bv1;
  #pragma unroll
  for (int j = 0; j < 8; ++j){
    int v = 8 * g + j;
    float val0 = 0.f, val1 = 0.f;
    if (v < cV){
      float xv = x1p[v];
      float e0 = __expf(2.f * (xv - w0));
      val0 = __fdividef(e0 - 1.f, e0 + 1.f) * a0 + Ak[v*cV + l15] + adak[v*cV + l15];
      if (w1i < cV){
        float e1 = __expf(2.f * (xv - w1));
        val1 = __fdividef(e1 - 1.f, e1 + 1.f) * a0 + Ak[v*cV + w1i] + adak[v*cV + w1i];
      }
    }
    bv0[j] = (short)f2bu(val0);
    bv1[j] = (short)f2bu(val1);
  }

  const ushort* pb = g_pre32 + ((size_t)n * cKM + r) * cPC;
  f32x4 acc[4][2];
  #pragma unroll
  for (int mf = 0; mf < 4; ++mf){
    s16x8 av = *(const s16x8*)(pb + (16*mf + l15) * 32 + 8*g);
    acc[mf][0] = __builtin_amdgcn_mfma_f32_16x16x32_bf16(av, bv0, (f32x4){0.f,0.f,0.f,0.f}, 0, 0, 0);
    acc[mf][1] = __builtin_amdgcn_mfma_f32_16x16x32_bf16(av, bv1, (f32x4){0.f,0.f,0.f,0.f}, 0, 0, 0);
  }

  // repack D -> LDS (compact [t][25])
  #pragma unroll
  for (int mf = 0; mf < 4; ++mf)
    #pragma unroll
    for (int nf = 0; nf < 2; ++nf)
      #pragma unroll
      for (int q = 0; q < 4; ++q){
        int t = 16*mf + 4*g + q, w = 16*nf + l15;
        if (w < cV) yst[wv][t * cV + w] = f2bu(acc[mf][nf][q]);
      }
  __syncthreads();
  // write phase: 2048 padded cols x 16B chunks, coalesced
  ushort* zp = g_ztP + ((size_t)n * 32 + oct) * cPC * 8;
  #pragma unroll
  for (int c0 = 0; c0 < cPC; c0 += 512){
    int c = c0 + tid;
    int t = c >> 5, v = c & 31;
    ushort u[8];
    if (v < cV){
      #pragma unroll
      for (int w8 = 0; w8 < 8; ++w8) u[w8] = yst[w8][t * cV + v];
    } else {
      #pragma unroll
      for (int w8 = 0; w8 < 8; ++w8) u[w8] = 0;
    }
    *(uint4*)(zp + (size_t)c * 8) = *(const uint4*)u;
  }
}

// ---------------------------------------------------------------------------
extern "C" void kernel_launch(void* const* d_in, const int* in_sizes, int n_in,
                              void* d_out, int out_size, void* d_ws, size_t ws_size,
                              hipStream_t stream){
  (void)in_sizes; (void)n_in; (void)out_size; (void)d_ws; (void)ws_size;
  const float* x      = (const float*)d_in[0];
  const float* A      = (const float*)d_in[1];
  const float* alpha  = (const float*)d_in[2];
  const float* beta   = (const float*)d_in[3];
  const float* W_pre  = (const float*)d_in[4];
  const float* b_pre  = (const float*)d_in[5];
  const float* bn_pre = (const float*)d_in[6];
  const float* W1     = (const float*)d_in[7];
  const float* b1     = (const float*)d_in[8];
  const float* W2     = (const float*)d_in[9];
  const float* b2     = (const float*)d_in[10];
  const float* W_post = (const float*)d_in[11];
  const float* b_post = (const float*)d_in[12];
  const float* bn_post= (const float*)d_in[13];
  const float* W_down = (const float*)d_in[14];
  const float* b_down = (const float*)d_in[15];
  const float* bn_down= (const float*)d_in[16];
  float* out = (float*)d_out;

  k_fold  <<<1,         256, 0, stream>>>(W_pre, b_pre, bn_pre,
                                          W_post, b_post, bn_post,
                                          W_down, b_down, bn_down);
  gm_tmp  <<<cN * cC,    64, 0, stream>>>(x);
  gm_x1x2 <<<cN * 4,    256, 0, stream>>>(W1, b1, W2, b2);
  gm_ada  <<<cN * cK,   128, 0, stream>>>(beta);
  k_xt    <<<cN * 8,    256, 0, stream>>>(x);
  gm_mm<0><<<cN * 32,   256, 0, stream>>>(nullptr);
  gm_y2   <<<cN * 24,   512, 0, stream>>>(A, alpha);
  gm_mm<1><<<cN * 32,   256, 0, stream>>>(out);
}

// Round 10
// 247.330 us; speedup vs baseline: 1.1603x; 1.1603x over previous
//
#include <hip/hip_runtime.h>
#include <hip/hip_bf16.h>

typedef __hip_bfloat16 bf16;
typedef __attribute__((ext_vector_type(8))) short s16x8;
typedef __attribute__((ext_vector_type(4))) float f32x4;

constexpr int cN = 128, cC = 64, cT = 64, cV = 25, cK = 3, cMID = 64, cKM = 192, cTV = 1600;
constexpr float cEPS = 1e-5f;

// BSS intermediates (no d_ws use). All rewritten before read each call.
__device__ float g_tmp[cN * cC * cV];
__device__ float g_x1 [cN * cKM * cV];
__device__ float g_x2 [cN * cKM * cV];
__device__ float g_ada[cN * cK * cV * cV];
// Per-channel Adyn in B-fragment order: [n][r][nf(2)][lane(64)][j(8)] bf16
__device__ ushort g_adF[(size_t)cN * cKM * 1024];          // 50.3 MB
// Folded weights in A-fragment order: [k-step][m-frag(12)][lane(64)][8]
__device__ ushort g_WpreF[2 * 12 * 512];
__device__ ushort g_WcatF[8 * 12 * 512];
__device__ float g_bpre [cKM];
__device__ float g_cterm[cKM];

__device__ __forceinline__ bf16  f2b(float v){ return __float2bfloat16(v); }
__device__ __forceinline__ ushort f2bu(float v){ return __builtin_bit_cast(ushort, __float2bfloat16(v)); }

// ---------------------------------------------------------------------------
// 0) fold bn into weights/biases; weights stored in A-frag order (bf16).
// ---------------------------------------------------------------------------
__global__ void k_fold(const float* __restrict__ Wpre, const float* __restrict__ bpre,
                       const float* __restrict__ bnpre,
                       const float* __restrict__ Wpost, const float* __restrict__ bpost,
                       const float* __restrict__ bnpost,
                       const float* __restrict__ Wdown, const float* __restrict__ bdown,
                       const float* __restrict__ bndown){
  __shared__ float sPre[cKM], sPost[cKM], sDown[cKM];
  int tid = threadIdx.x;
  if (tid < cKM){
    float sp = bnpre[tid] * rsqrtf(bnpre[3*cKM+tid] + cEPS);
    sPre[tid] = sp;
    g_bpre[tid] = bpre[tid]*sp + bnpre[cKM+tid] - bnpre[2*cKM+tid]*sp;
    float sP = bnpost[tid] * rsqrtf(bnpost[3*cKM+tid] + cEPS);
    float sD = bndown[tid] * rsqrtf(bndown[3*cKM+tid] + cEPS);
    sPost[tid] = sP; sDown[tid] = sD;
    g_cterm[tid] = bpost[tid]*sP + bnpost[cKM+tid] - bnpost[2*cKM+tid]*sP
                 + bdown[tid]*sD + bndown[cKM+tid] - bndown[2*cKM+tid]*sD;
  }
  __syncthreads();
  for (int idx = tid; idx < cKM*cC; idx += 256){
    int o = idx >> 6, k = idx & 63;
    int step = k >> 5, g = (k >> 3) & 3, j = k & 7;
    int dst = ((step*12 + (o>>4)) << 9) + (((g<<4) | (o&15)) << 3) + j;
    g_WpreF[dst] = f2bu(Wpre[idx] * sPre[o]);
  }
  for (int idx = tid; idx < cKM*256; idx += 256){
    int o = idx >> 8, k = idx & 255;
    float w = (k < cKM) ? Wpost[o*cKM + k] * sPost[o]
                        : Wdown[o*cC + (k - cKM)] * sDown[o];
    int step = k >> 5, g = (k >> 3) & 3, j = k & 7;
    int dst = ((step*12 + (o>>4)) << 9) + (((g<<4) | (o&15)) << 3) + j;
    g_WcatF[dst] = f2bu(w);
  }
}

// ---------------------------------------------------------------------------
// 1) g_tmp[n,c,v] = mean_t x[n,c,t,v]   coalesced via LDS.  grid = N*16.
// ---------------------------------------------------------------------------
__global__ __launch_bounds__(256) void gm_tmp(const float* __restrict__ x){
  __shared__ float xs[4 * cTV];
  int n = blockIdx.x >> 4, cg = blockIdx.x & 15;
  int tid = threadIdx.x;
  const float* xp = x + ((size_t)n*cC + cg*4)*cTV;
  for (int i = tid; i < 4*cTV; i += 256) xs[i] = xp[i];
  __syncthreads();
  if (tid < 100){
    int c = tid / 25, v = tid - c*25;
    float s = 0.f;
    #pragma unroll
    for (int t = 0; t < cT; ++t) s += xs[c*cTV + t*cV + v];
    g_tmp[(n*cC + cg*4 + c)*cV + v] = s * (1.f/cT);
  }
}

// ---------------------------------------------------------------------------
// 2) x1/x2 1x1 conv on mean
// ---------------------------------------------------------------------------
__global__ void gm_x1x2(const float* __restrict__ W1, const float* __restrict__ b1,
                        const float* __restrict__ W2, const float* __restrict__ b2){
  __shared__ float tl[cC * cV];
  __shared__ float w1[48 * cC];
  __shared__ float w2[48 * cC];
  int n = blockIdx.x >> 2, og = blockIdx.x & 3;
  int tid = threadIdx.x;
  int obase = og * 48;
  for (int i = tid; i < cC * cV; i += 256) tl[i] = g_tmp[n * cC * cV + i];
  for (int i = tid; i < 48 * cC; i += 256){
    w1[i] = W1[obase * cC + i];
    w2[i] = W2[obase * cC + i];
  }
  __syncthreads();
  for (int idx = tid; idx < 48 * cV; idx += 256){
    int j = idx / cV, v = idx % cV;
    int o = obase + j;
    float s1 = b1[o], s2 = b2[o];
    #pragma unroll
    for (int c = 0; c < cC; ++c){
      float t = tl[c * cV + v];
      s1 += w1[j * cC + c] * t;
      s2 += w2[j * cC + c] * t;
    }
    g_x1[((size_t)n * cKM + o) * cV + v] = s1;
    g_x2[((size_t)n * cKM + o) * cV + v] = s2;
  }
}

// ---------------------------------------------------------------------------
// 3) ada softmax (channel-shared part of Adyn)
// ---------------------------------------------------------------------------
__global__ void gm_ada(const float* __restrict__ beta){
  __shared__ float a1[cMID * cV];
  __shared__ float a2[cMID * cV];
  __shared__ float al[cV * cV];
  int b = blockIdx.x; int n = b / cK, k = b % cK;
  int tid = threadIdx.x;
  const float* p1 = g_x1 + ((size_t)n * cKM + k * cMID) * cV;
  const float* p2 = g_x2 + ((size_t)n * cKM + k * cMID) * cV;
  for (int i = tid; i < cMID * cV; i += 128){ a1[i] = p1[i]; a2[i] = p2[i]; }
  __syncthreads();
  for (int idx = tid; idx < cV * cV; idx += 128){
    int v = idx / cV, w = idx % cV;
    float s = 0.f;
    #pragma unroll
    for (int c = 0; c < cMID; ++c) s += a1[c * cV + v] * a2[c * cV + w];
    al[idx] = s;
  }
  __syncthreads();
  float b0 = beta[0];
  if (tid < cV){
    int w = tid;
    float m = -1e30f;
    for (int v = 0; v < cV; ++v) m = fmaxf(m, al[v * cV + w]);
    float s = 0.f;
    for (int v = 0; v < cV; ++v) s += expf(al[v * cV + w] - m);
    float inv = b0 / s;
    for (int v = 0; v < cV; ++v)
      g_ada[(size_t)b * cV * cV + v * cV + w] = expf(al[v * cV + w] - m) * inv;
  }
}

// ---------------------------------------------------------------------------
// 3b) Per-channel Adyn -> B-fragment order g_adF[n][r][nf][lane][8].
//     B-frag value(lane g,l15; reg j) = Adyn[v=8g+j][w=16nf+l15], 0 outside.
//     grid = N*24 (8 channels each), 256 thr.
// ---------------------------------------------------------------------------
__global__ __launch_bounds__(256) void gm_adFk(const float* __restrict__ A,
                                               const float* __restrict__ alpha){
  int n = blockIdx.x / 24, rg = blockIdx.x % 24;
  int tid = threadIdx.x;
  float a0 = alpha[0];
  #pragma unroll 1
  for (int it = 0; it < 32; ++it){
    int idx = it*256 + tid;                 // 0..8191
    int ch_i = idx >> 10, rem = idx & 1023;
    int nf = rem >> 9, rem2 = rem & 511;
    int lane_i = rem2 >> 3, j = rem2 & 7;
    int gg = lane_i >> 4, ll = lane_i & 15;
    int v = 8*gg + j, w = 16*nf + ll;
    int r = rg*8 + ch_i, kg = r >> 6;
    float val = 0.f;
    if (v < cV && w < cV){
      float xv = g_x1[((size_t)n*cKM + r)*cV + v];
      float xw = g_x2[((size_t)n*cKM + r)*cV + w];
      float e = __expf(2.f*(xv - xw));
      val = __fdividef(e - 1.f, e + 1.f)*a0 + A[kg*625 + v*cV + w]
          + g_ada[((size_t)n*cK + kg)*625 + v*cV + w];
    }
    g_adF[((size_t)n*cKM + r)*1024 + rem] = f2bu(val);
  }
}

// ---------------------------------------------------------------------------
// 4) FUSED pre -> per-channel map -> out.  One block per (n, 4-t tile).
//    512 thr = 8 waves.  LDS: Z 64 KB (octets 24..31 = x, 0..23 = y) +
//    Pt 16 KB (pre transpose scratch, [row=t*64+o][g][8]).
// ---------------------------------------------------------------------------
__global__ __launch_bounds__(512, 4) void gm_fused(const float* __restrict__ x,
                                                   float* __restrict__ outf){
  __shared__ ushort Zl[32 * 128 * 8];      // 64 KB [oct][col][j]
  __shared__ ushort Pt[256 * 4 * 8];       // 16 KB [row][g][j]
  int bid = (int)(blockIdx.x & 7) * 256 + ((int)blockIdx.x >> 3);  // XCD swizzle
  int n = bid >> 4, ttile = bid & 15;
  int t0 = ttile * 4;
  int tid = threadIdx.x;
  int wv = tid >> 6, lane = tid & 63, g = lane >> 4, l15 = lane & 15;
  int mfh = wv >> 1;          // 0..3
  int nfh = wv & 1;           // 0..1

  // ---- stage x -> Z octets 24..31 (pads zero) ----
  #pragma unroll
  for (int s0 = 0; s0 < 1024; s0 += 512){
    int s = s0 + tid;
    int oct = s >> 7, col = s & 127;
    int t = col >> 5, v = col & 31;
    ushort u[8];
    if (v < cV){
      const float* xp = x + ((size_t)n*cC + oct*8)*cTV + (t0 + t)*cV + v;
      #pragma unroll
      for (int j = 0; j < 8; ++j) u[j] = f2bu(xp[(size_t)j*cTV]);
    } else {
      #pragma unroll
      for (int j = 0; j < 8; ++j) u[j] = 0;
    }
    *(uint4*)&Zl[((24 + oct)*128 + col)*8] = *(const uint4*)u;
  }

  #pragma unroll 1
  for (int kg = 0; kg < 3; ++kg){
    __syncthreads();   // kg=0: x staged; kg>0: Pt safe to overwrite
    // ---- GEMM1: pre rows kg*64..kg*64+63, 128 cols ----
    f32x4 a1[4];
    #pragma unroll
    for (int nn = 0; nn < 4; ++nn) a1[nn] = (f32x4){0.f,0.f,0.f,0.f};
    #pragma unroll
    for (int ks = 0; ks < 2; ++ks){
      s16x8 av = *(const s16x8*)(g_WpreF + ((ks*12 + kg*4 + mfh) << 9) + lane*8);
      #pragma unroll
      for (int nn = 0; nn < 4; ++nn){
        int col = 16*(nfh*4 + nn) + l15;
        s16x8 bv = *(const s16x8*)&Zl[((24 + ks*4 + g)*128 + col)*8];
        a1[nn] = __builtin_amdgcn_mfma_f32_16x16x32_bf16(av, bv, a1[nn], 0, 0, 0);
      }
    }
    // bias+relu -> Pt (zero pads)
    #pragma unroll
    for (int nn = 0; nn < 4; ++nn){
      int col = 16*(nfh*4 + nn) + l15;
      int t = col >> 5, v = col & 31;
      #pragma unroll
      for (int q = 0; q < 4; ++q){
        int o = 16*mfh + 4*g + q;
        float val = (v < cV) ? fmaxf(a1[nn][q] + g_bpre[kg*64 + o], 0.f) : 0.f;
        Pt[((t*64 + o)*4 + (v>>3))*8 + (v&7)] = f2bu(val);
      }
    }
    __syncthreads();
    // ---- GEMM2 per channel: D[t(pad16), w] = pre[t,v] @ Adyn[v,w] ----
    #pragma unroll 1
    for (int cc = 0; cc < 8; ++cc){
      int chl = wv*8 + cc;                 // 0..63
      int r = kg*64 + chl;
      s16x8 av;
      if (l15 < 4) av = *(const s16x8*)&Pt[((l15*64 + chl)*4 + g)*8];
      else         av = (s16x8){0,0,0,0,0,0,0,0};
      const ushort* bp = g_adF + ((size_t)n*cKM + r)*1024;
      #pragma unroll
      for (int nf = 0; nf < 2; ++nf){
        s16x8 bv = *(const s16x8*)(bp + nf*512 + lane*8);
        f32x4 d = __builtin_amdgcn_mfma_f32_16x16x32_bf16(av, bv, (f32x4){0.f,0.f,0.f,0.f}, 0, 0, 0);
        if (g == 0){
          #pragma unroll
          for (int q = 0; q < 4; ++q){     // q = t
            Zl[((kg*8 + (chl>>3))*128 + q*32 + 16*nf + l15)*8 + (chl&7)] = f2bu(d[q]);
          }
        }
      }
    }
  }
  __syncthreads();
  // ---- GEMM3: out[192][128] = Wcat[192][256] @ Z ----
  f32x4 a3[3][4];
  #pragma unroll
  for (int mm = 0; mm < 3; ++mm)
    #pragma unroll
    for (int nn = 0; nn < 4; ++nn) a3[mm][nn] = (f32x4){0.f,0.f,0.f,0.f};
  #pragma unroll 2
  for (int ks = 0; ks < 8; ++ks){
    s16x8 av[3], bv[4];
    #pragma unroll
    for (int mm = 0; mm < 3; ++mm)
      av[mm] = *(const s16x8*)(g_WcatF + ((ks*12 + mfh*3 + mm) << 9) + lane*8);
    #pragma unroll
    for (int nn = 0; nn < 4; ++nn){
      int col = 16*(nfh*4 + nn) + l15;
      bv[nn] = *(const s16x8*)&Zl[((ks*4 + g)*128 + col)*8];
    }
    #pragma unroll
    for (int mm = 0; mm < 3; ++mm)
      #pragma unroll
      for (int nn = 0; nn < 4; ++nn)
        a3[mm][nn] = __builtin_amdgcn_mfma_f32_16x16x32_bf16(av[mm], bv[nn], a3[mm][nn], 0, 0, 0);
  }
  // epilogue: bias + relu -> d_out (f32)
  #pragma unroll
  for (int mm = 0; mm < 3; ++mm){
    #pragma unroll
    for (int q = 0; q < 4; ++q){
      int o = 48*mfh + 16*mm + 4*g + q;
      float ct = g_cterm[o];
      #pragma unroll
      for (int nn = 0; nn < 4; ++nn){
        int col = 16*(nfh*4 + nn) + l15;
        int t = col >> 5, v = col & 31;
        if (v < cV)
          outf[((size_t)n*cKM + o)*cTV + (t0 + t)*cV + v] = fmaxf(a3[mm][nn][q] + ct, 0.f);
      }
    }
  }
}

// ---------------------------------------------------------------------------
extern "C" void kernel_launch(void* const* d_in, const int* in_sizes, int n_in,
                              void* d_out, int out_size, void* d_ws, size_t ws_size,
                              hipStream_t stream){
  (void)in_sizes; (void)n_in; (void)out_size; (void)d_ws; (void)ws_size;
  const float* x      = (const float*)d_in[0];
  const float* A      = (const float*)d_in[1];
  const float* alpha  = (const float*)d_in[2];
  const float* beta   = (const float*)d_in[3];
  const float* W_pre  = (const float*)d_in[4];
  const float* b_pre  = (const float*)d_in[5];
  const float* bn_pre = (const float*)d_in[6];
  const float* W1     = (const float*)d_in[7];
  const float* b1     = (const float*)d_in[8];
  const float* W2     = (const float*)d_in[9];
  const float* b2     = (const float*)d_in[10];
  const float* W_post = (const float*)d_in[11];
  const float* b_post = (const float*)d_in[12];
  const float* bn_post= (const float*)d_in[13];
  const float* W_down = (const float*)d_in[14];
  const float* b_down = (const float*)d_in[15];
  const float* bn_down= (const float*)d_in[16];
  float* out = (float*)d_out;

  k_fold  <<<1,        256, 0, stream>>>(W_pre, b_pre, bn_pre,
                                         W_post, b_post, bn_post,
                                         W_down, b_down, bn_down);
  gm_tmp  <<<cN * 16,  256, 0, stream>>>(x);
  gm_x1x2 <<<cN * 4,   256, 0, stream>>>(W1, b1, W2, b2);
  gm_ada  <<<cN * cK,  128, 0, stream>>>(beta);
  gm_adFk <<<cN * 24,  256, 0, stream>>>(A, alpha);
  gm_fused<<<cN * 16,  512, 0, stream>>>(x, out);
}